// Round 11
// baseline (779.094 us; speedup 1.0000x reference)
//
#include <hip/hip_runtime.h>
#include <hip/hip_bf16.h>

typedef __hip_bfloat16 bf16;
typedef short short8 __attribute__((ext_vector_type(8)));   // 8 bf16 bit-patterns (4 VGPRs)
typedef short short4v __attribute__((ext_vector_type(4)));
typedef float floatx4 __attribute__((ext_vector_type(4)));
typedef int int4v __attribute__((ext_vector_type(4)));

#define DIMC 1152
#define NTOK 8192    // B*N
#define NSEQ 4096
#define HD 72
#define HDP 73       // HD + 1 (padded-ones value column)
#define HIDC 4608
#define HID2 9216
#define QKVN 3456    // 3*DIMC
#define KVH (HD * HDP)            // 5256 per (b,h)
#define PZ ((size_t)2048 * DIMC)  // split-K partial plane (2048-row chunk, fallback)
#define PZB ((size_t)4096 * DIMC) // split-K partial plane (per-batch fallback)

// attn_kv MFMA geometry
#define DP 96        // padded d/e extent (6 x 16)
#define KVNT 128     // tokens per LDS tile
#define KV_NITER 2   // LDS tiles per block
#define KV_CHUNKS 16 // chunks per batch (16 * 256 = 4096 tokens)

__device__ __forceinline__ float b2f(bf16 x) { return __bfloat162float(x); }
__device__ __forceinline__ bf16 f2b(float x) { return __float2bfloat16(x); }
__device__ __forceinline__ void st(float* p, float v) { *p = v; }
__device__ __forceinline__ void st(bf16* p, float v)  { *p = f2b(v); }
__device__ __forceinline__ float tf(float x) { return x; }
__device__ __forceinline__ float tf(bf16 x)  { return __bfloat162float(x); }
__device__ __forceinline__ float s2f(short s) {
    unsigned int u = ((unsigned int)(unsigned short)s) << 16;
    return __uint_as_float(u);
}
__device__ __forceinline__ short f2s(float f) {
    bf16 h = f2b(f);
    return *reinterpret_cast<short*>(&h);
}

// async global->LDS DMA, 16B per lane. LDS dest is wave-uniform base + lane*16.
__device__ __forceinline__ void gload_lds16(const bf16* g, short* l) {
    __builtin_amdgcn_global_load_lds(
        (const __attribute__((address_space(1))) void*)g,
        (__attribute__((address_space(3))) void*)l, 16, 0, 0);
}

// ---------------- setup: weight cvt (f32->bf16, two dst regions) + mods + bias3 + kv zero ----------------
// blocks [0,20736): cvt. dstA (f4 [0,1327104)): Wq|Wk|Wv|Wo. dstB: Winv|Wpt.
// blocks [20736,21452): i<13824 mods; i<14976 bias3; i<183168 kv zero (32*KVH).
__global__ void setup_kernel(const float* __restrict__ s0, const float* __restrict__ s1,
                             const float* __restrict__ s2, const float* __restrict__ s3,
                             const float* __restrict__ s4, const float* __restrict__ s5,
                             bf16* __restrict__ dstA, bf16* __restrict__ dstB,
                             const float* __restrict__ sst, const float* __restrict__ temb,
                             float* __restrict__ mods, const float* __restrict__ ba,
                             const float* __restrict__ bb, const float* __restrict__ bc,
                             float* __restrict__ bq, float* __restrict__ kvz) {
    int gb = blockIdx.x;
    if (gb < 20736) {
        int i = gb * 256 + threadIdx.x;   // float4 index, total 5308416
        if (i >= 5308416) return;
        const float* src; int base, ib; bf16* dst;
        if (i < 1327104) {
            dst = dstA; ib = i;
            if (i < 331776)      { src = s0; base = 0; }
            else if (i < 663552) { src = s1; base = 331776; }
            else if (i < 995328) { src = s2; base = 663552; }
            else                 { src = s3; base = 995328; }
        } else {
            dst = dstB; ib = i - 1327104;
            if (i < 3981312)     { src = s4; base = 1327104; }
            else                 { src = s5; base = 3981312; }
        }
        floatx4 v = ((const floatx4*)src)[i - base];
        bf16* o = dst + (size_t)ib * 4;
        o[0] = f2b(v[0]); o[1] = f2b(v[1]); o[2] = f2b(v[2]); o[3] = f2b(v[3]);
    } else {
        int i = (gb - 20736) * 256 + threadIdx.x;
        if (i < 13824) {
            mods[i] = sst[i % (6 * DIMC)] + temb[i];
        } else if (i < 13824 + DIMC) {
            int j = i - 13824;
            bq[j] = ba[j]; bq[j + DIMC] = bb[j]; bq[j + 2 * DIMC] = bc[j];
        } else if (i < 13824 + DIMC + 32 * KVH) {
            kvz[i - 13824 - DIMC] = 0.0f;
        }
    }
}

// ---------------- x = rms(h)*(1+scale)+shift; out bf16. Vectorized 8/thread, single read ----------------
template<typename T>
__global__ void rmsmod_kernel(const T* __restrict__ h, const float* __restrict__ mods,
                              int shift_idx, int scale_idx, bf16* __restrict__ xout) {
    int token = blockIdx.x;            // 0..8191
    int b = token >> 12;
    int tid = threadIdx.x;
    int wave = tid >> 6, lane = tid & 63;
    const T* hp = h + (size_t)token * DIMC;

    float v[8];
    float s = 0.f;
    if (tid < 144) {                   // 144*8 = 1152
        if constexpr (sizeof(T) == 4) {
            floatx4 a = *(const floatx4*)((const float*)hp + tid * 8);
            floatx4 c = *(const floatx4*)((const float*)hp + tid * 8 + 4);
            v[0]=a[0]; v[1]=a[1]; v[2]=a[2]; v[3]=a[3];
            v[4]=c[0]; v[5]=c[1]; v[6]=c[2]; v[7]=c[3];
        } else {
            short8 a = *(const short8*)((const short*)hp + tid * 8);
            #pragma unroll
            for (int j = 0; j < 8; j++) v[j] = s2f(a[j]);
        }
        #pragma unroll
        for (int j = 0; j < 8; j++) s += v[j] * v[j];
    }
    #pragma unroll
    for (int off = 32; off > 0; off >>= 1) s += __shfl_down(s, off);
    __shared__ float wsum[4];
    if (lane == 0) wsum[wave] = s;
    __syncthreads();
    float tot = wsum[0] + wsum[1] + wsum[2] + wsum[3];
    float r = rsqrtf(tot / (float)DIMC + 1e-6f);

    if (tid < 144) {
        const float* sh = mods + (size_t)(b * 6 + shift_idx) * DIMC + tid * 8;
        const float* sc = mods + (size_t)(b * 6 + scale_idx) * DIMC + tid * 8;
        floatx4 sh0 = *(const floatx4*)sh, sh1 = *(const floatx4*)(sh + 4);
        floatx4 sc0 = *(const floatx4*)sc, sc1 = *(const floatx4*)(sc + 4);
        short8 o;
        o[0] = f2s(v[0] * r * (1.f + sc0[0]) + sh0[0]);
        o[1] = f2s(v[1] * r * (1.f + sc0[1]) + sh0[1]);
        o[2] = f2s(v[2] * r * (1.f + sc0[2]) + sh0[2]);
        o[3] = f2s(v[3] * r * (1.f + sc0[3]) + sh0[3]);
        o[4] = f2s(v[4] * r * (1.f + sc1[0]) + sh1[0]);
        o[5] = f2s(v[5] * r * (1.f + sc1[1]) + sh1[1]);
        o[6] = f2s(v[6] * r * (1.f + sc1[2]) + sh1[2]);
        o[7] = f2s(v[7] * r * (1.f + sc1[3]) + sh1[3]);
        *(short8*)((short*)xout + (size_t)token * DIMC + tid * 8) = o;
    }
}

// ---------------- 128x128 MFMA GEMM (m97-structure, BK=64, both-sides swizzle) ----------------
// MODE 0: QKV fused: acc+bias, relu iff col<2304      -> bf16 (N=3456)
// MODE 2: gate*(acc+bias)+resid(f32)                   -> bf16 trunk
// MODE 3: silu(acc+bias)                               -> bf16
// MODE 5: raw partial acc (split-K via blockIdx.z)     -> f32 at zstride*z
// MODE 6: trunk(bf16 via resid) + mods[gate]*acc       -> f32 (fused W_pt + reduce, full K)
template<int MODE, typename OT>
__global__ __launch_bounds__(256, 2)
void gemm_kernel(const bf16* __restrict__ A, const bf16* __restrict__ W,
                 const float* __restrict__ bias, const float* __restrict__ mods,
                 int gate_idx, int m_off, const float* __restrict__ resid,
                 OT* __restrict__ out, int N, int Kfull, int Klen,
                 size_t zstride, int bm_lo, int bm_hi) {
    const int bm = blockIdx.x;
    if (bm < bm_lo || bm >= bm_hi) return;
    const int koff = blockIdx.z * Klen;
    __shared__ __align__(16) short As[128 * 64];   // [128 rows][64 k] linear (row=128B)
    __shared__ __align__(16) short Bs[128 * 64];
    const int tid = threadIdx.x;
    const int wave = tid >> 6;
    const int lane = tid & 63;
    const int quad = lane >> 4;
    const int l16 = lane & 15;
    const int wm = (wave & 1) * 64;
    const int wn = (wave >> 1) * 64;
    const int bn = blockIdx.y;

    floatx4 acc[4][4];
    #pragma unroll
    for (int i = 0; i < 4; i++)
        #pragma unroll
        for (int j = 0; j < 4; j++)
            #pragma unroll
            for (int r = 0; r < 4; r++) acc[i][j][r] = 0.0f;

    const int lrow8 = lane >> 3;                     // row within 8-row group == row&7
    const int scol = ((lane & 7) ^ lrow8) * 8;       // pre-swizzled source col (elems)
    const bf16* gA = A + (size_t)(bm * 128 + wave * 8 + lrow8) * Kfull + koff + scol;
    const bf16* gB = W + (size_t)(bn * 128 + wave * 8 + lrow8) * Kfull + koff + scol;
    short* lA = &As[wave * 512];
    short* lB = &Bs[wave * 512];
    const size_t rstep = (size_t)32 * Kfull;         // 32 rows between issues

    for (int k0 = 0; k0 < Klen; k0 += 64) {
        __syncthreads();
        #pragma unroll
        for (int j = 0; j < 4; j++) gload_lds16(gA + j * rstep + k0, lA + j * 2048);
        #pragma unroll
        for (int j = 0; j < 4; j++) gload_lds16(gB + j * rstep + k0, lB + j * 2048);
        __syncthreads();
        short8 af[2][4], bfr[2][4];
        #pragma unroll
        for (int i = 0; i < 4; i++) {
            const int ra = wm + i * 16 + l16;
            const int rb = wn + i * 16 + l16;
            #pragma unroll
            for (int kk = 0; kk < 2; kk++) {
                af[kk][i]  = *(const short8*)&As[ra * 64 + (((kk * 4 + quad) ^ (ra & 7)) * 8)];
                bfr[kk][i] = *(const short8*)&Bs[rb * 64 + (((kk * 4 + quad) ^ (rb & 7)) * 8)];
            }
        }
        #pragma unroll
        for (int kk = 0; kk < 2; kk++)
            #pragma unroll
            for (int i = 0; i < 4; i++)
                #pragma unroll
                for (int j = 0; j < 4; j++)
                    acc[i][j] = __builtin_amdgcn_mfma_f32_16x16x32_bf16(af[kk][i], bfr[kk][j], acc[i][j], 0, 0, 0);
    }

    #pragma unroll
    for (int i = 0; i < 4; i++) {
        #pragma unroll
        for (int j = 0; j < 4; j++) {
            const int col = bn * 128 + wn + j * 16 + l16;
            #pragma unroll
            for (int r = 0; r < 4; r++) {
                const int m = bm * 128 + wm + i * 16 + quad * 4 + r;
                float v = acc[i][j][r];
                float o;
                if (MODE == 0) {
                    o = v + bias[col];
                    if (col < 2 * DIMC) o = fmaxf(o, 0.f);
                } else if (MODE == 2) {
                    int b = (m + m_off) >> 12;
                    o = mods[(size_t)(b * 6 + gate_idx) * DIMC + col] * (v + bias[col])
                        + resid[(size_t)m * DIMC + col];
                } else if (MODE == 3) {
                    float sv = v + bias[col];
                    o = sv / (1.f + __expf(-sv));
                } else if (MODE == 6) {
                    const bf16* tr = (const bf16*)resid;         // trunk (bf16)
                    int b = m >> 12;
                    o = tf(tr[(size_t)m * DIMC + col])
                        + mods[(size_t)(b * 6 + gate_idx) * DIMC + col] * v;
                } else {  // MODE 5: raw partial
                    o = v;
                }
                st(&out[zstride * blockIdx.z + (size_t)m * N + col], o);
            }
        }
    }
}

// ---------------- split-K reduce (vectorized 4/thread): out = trunk + gate_mlp * sum(planes) ----------------
template<int NP>
__global__ void reduce_kernel(const float* __restrict__ part, const bf16* __restrict__ trunk,
                              const float* __restrict__ mods, int b, int r0, size_t pstride,
                              float* __restrict__ out) {
    int i4 = (blockIdx.x * 256 + threadIdx.x) * 4;
    int col = i4 % DIMC;                               // 4 cols contiguous (DIMC % 4 == 0)
    floatx4 s = *(const floatx4*)(part + i4);
    #pragma unroll
    for (int p = 1; p < NP; ++p) {
        floatx4 t = *(const floatx4*)(part + (size_t)p * pstride + i4);
        s[0] += t[0]; s[1] += t[1]; s[2] += t[2]; s[3] += t[3];
    }
    size_t gidx = ((size_t)b * NSEQ + r0) * DIMC + i4;
    short4v tr = *(const short4v*)((const short*)trunk + gidx);
    floatx4 g = *(const floatx4*)(mods + (size_t)(b * 6 + 5) * DIMC + col);
    floatx4 o;
    #pragma unroll
    for (int j = 0; j < 4; ++j) o[j] = s2f(tr[j]) + g[j] * s[j];
    *(floatx4*)(out + gidx) = o;
}

// ---------------- attention phase A (MFMA): kv[bh][d][e] += sum_n k[n,d]*vpad[n,e] ----------------
// Direct device-scope atomicAdd into kvb (zero-init by setup). 16 colliding adds per cell.
__device__ __forceinline__ int kvaddr(int row, int n) {   // short index
    return row * KVNT + ((((n >> 3) ^ (row & 7))) << 3) + (n & 7);
}

__global__ __launch_bounds__(256, 3)
void attn_kv_kernel(const bf16* __restrict__ qkv, float* __restrict__ kv) {
    const int chunk = blockIdx.x;   // 16 chunks of 256 tokens
    const int h = blockIdx.y;       // 16 heads
    const int b = blockIdx.z;       // 2 batches
    __shared__ __align__(16) short kl[DP * KVNT];   // 24 KB
    __shared__ __align__(16) short vl[DP * KVNT];   // 24 KB
    const int tid = threadIdx.x;
    const int wave = tid >> 6, lane = tid & 63;
    const int quad = lane >> 4, l16 = lane & 15;
    const int wd = (wave & 1) * 48;     // d-half
    const int we = (wave >> 1) * 48;    // e-half

    for (int i = tid; i < 24 * KVNT; i += 256) {
        kl[72 * KVNT + i] = 0;
        vl[72 * KVNT + i] = (i < KVNT) ? (short)0x3F80 : (short)0;   // row 72 = bf16 1.0
    }

    floatx4 acc[3][3];
    #pragma unroll
    for (int i = 0; i < 3; i++)
        #pragma unroll
        for (int j = 0; j < 3; j++)
            #pragma unroll
            for (int r = 0; r < 4; r++) acc[i][j][r] = 0.0f;

    const size_t tok0 = (size_t)b * NSEQ + (size_t)chunk * (KVNT * KV_NITER);
    for (int it = 0; it < KV_NITER; ++it) {
        __syncthreads();
        const short* rb = (const short*)qkv + (tok0 + (size_t)it * KVNT) * QKVN + h * HD;
        #pragma unroll
        for (int p = 0; p < 5; ++p) {
            int idx = p * 256 + tid;
            int o = idx >> 7, n = idx & 127;
            if (o < 9) {
                const short* g = rb + (size_t)n * QKVN + o * 8;
                short8 kk = *(const short8*)(g + DIMC);
                short8 vv = *(const short8*)(g + 2 * DIMC);
                #pragma unroll
                for (int j = 0; j < 8; ++j) {
                    kl[kvaddr(o * 8 + j, n)] = kk[j];
                    vl[kvaddr(o * 8 + j, n)] = vv[j];
                }
            }
        }
        __syncthreads();
        #pragma unroll
        for (int ks = 0; ks < 4; ++ks) {
            const int nb = ks * 32 + quad * 8;
            short8 af[3], bfv[3];
            #pragma unroll
            for (int i = 0; i < 3; ++i) {
                const int ra = wd + i * 16 + l16;
                const int rbn = we + i * 16 + l16;
                af[i]  = *(const short8*)&kl[ra * KVNT + ((((nb >> 3) ^ (ra & 7))) << 3)];
                bfv[i] = *(const short8*)&vl[rbn * KVNT + ((((nb >> 3) ^ (rbn & 7))) << 3)];
            }
            #pragma unroll
            for (int i = 0; i < 3; ++i)
                #pragma unroll
                for (int j = 0; j < 3; ++j)
                    acc[i][j] = __builtin_amdgcn_mfma_f32_16x16x32_bf16(af[i], bfv[j], acc[i][j], 0, 0, 0);
        }
    }

    float* op = kv + (size_t)(b * 16 + h) * KVH;
    #pragma unroll
    for (int i = 0; i < 3; ++i) {
        const int dbase = wd + i * 16 + quad * 4;
        #pragma unroll
        for (int j = 0; j < 3; ++j) {
            const int e = we + j * 16 + l16;
            if (e < HDP) {
                #pragma unroll
                for (int r = 0; r < 4; ++r) {
                    const int d = dbase + r;
                    if (d < HD) atomicAdd(&op[d * HDP + e], acc[i][j][r]);
                }
            }
        }
    }
}

// ---------------- attention phase B (MFMA): Out[n][e] = Q[n][:]·KVT[e][:]; out = num/den ----------------
__global__ __launch_bounds__(256, 2)
void attn_out_kernel(const bf16* __restrict__ qkv, const float* __restrict__ kv,
                     bf16* __restrict__ outa) {
    const int chunk = blockIdx.x;   // 32 chunks of 128 tokens
    const int h = blockIdx.y;       // 16 heads
    const int b = blockIdx.z;       // 2 batches
    __shared__ __align__(16) short ql[128 * 128];   // 32 KB
    __shared__ __align__(16) short kvt[80 * 128];   // 20 KB
    const int tid = threadIdx.x;
    const int wave = tid >> 6, lane = tid & 63;
    const int quad = lane >> 4, l16 = lane & 15;
    const int wm = wave * 32;       // 2 M-frags (32 token-rows) per wave

    // stage Q: 128 rows x 16 slots = 2048 tasks; slots 9..15 zero (d >= 72)
    const short* qbase = (const short*)qkv + ((size_t)(b * NSEQ) + (size_t)chunk * 128) * QKVN + h * HD;
    #pragma unroll
    for (int t = 0; t < 8; ++t) {
        int idx = t * 256 + tid;
        int o = idx >> 7, n = idx & 127;
        short8 vv = {0, 0, 0, 0, 0, 0, 0, 0};
        if (o < 9) vv = *(const short8*)(qbase + (size_t)n * QKVN + o * 8);
        *(short8*)&ql[n * 128 + ((o ^ (n & 7)) << 3)] = vv;
    }
    // stage KVT: 80 e-rows x 16 slots = 1280 tasks; kv is f32 [d*73+e] per (b,h)
    const float* kp = kv + (size_t)(b * 16 + h) * KVH;
    #pragma unroll
    for (int t = 0; t < 5; ++t) {
        int idx = t * 256 + tid;
        int o = idx / 80, e = idx - (idx / 80) * 80;
        short8 vv = {0, 0, 0, 0, 0, 0, 0, 0};
        if (e < HDP && o < 9) {
            #pragma unroll
            for (int j = 0; j < 8; ++j) {
                int d = o * 8 + j;
                if (d < HD) vv[j] = f2s(kp[(size_t)d * HDP + e]);
            }
        }
        *(short8*)&kvt[e * 128 + ((o ^ (e & 7)) << 3)] = vv;
    }
    __syncthreads();

    floatx4 acc[2][5];
    #pragma unroll
    for (int i = 0; i < 2; ++i)
        #pragma unroll
        for (int j = 0; j < 5; ++j)
            #pragma unroll
            for (int r = 0; r < 4; ++r) acc[i][j][r] = 0.0f;

    #pragma unroll
    for (int kk = 0; kk < 3; ++kk) {
        const int s = kk * 4 + quad;                 // k-slot 0..11 (d = s*8..s*8+7)
        short8 af[2];
        #pragma unroll
        for (int i = 0; i < 2; ++i) {
            const int ra = wm + i * 16 + l16;
            af[i] = *(const short8*)&ql[ra * 128 + ((s ^ (ra & 7)) << 3)];
        }
        #pragma unroll
        for (int j = 0; j < 5; ++j) {
            const int rb = j * 16 + l16;
            short8 bfv = *(const short8*)&kvt[rb * 128 + ((s ^ (rb & 7)) << 3)];
            #pragma unroll
            for (int i = 0; i < 2; ++i)
                acc[i][j] = __builtin_amdgcn_mfma_f32_16x16x32_bf16(af[i], bfv, acc[i][j], 0, 0, 0);
        }
    }

    // epilogue: den[row] = output col 72 = N-frag 4, l16 == 8; shfl-broadcast within quad
    #pragma unroll
    for (int i = 0; i < 2; ++i) {
        #pragma unroll
        for (int r = 0; r < 4; ++r) {
            float den = __shfl(acc[i][4][r], (lane & 48) | 8);
            float inv = 1.0f / (den + 1e-15f);
            const int m = wm + i * 16 + quad * 4 + r;        // token within chunk
            bf16* op = outa + ((size_t)(b * NSEQ) + (size_t)chunk * 128 + m) * DIMC + h * HD;
            #pragma unroll
            for (int j = 0; j < 5; ++j) {
                const int e = j * 16 + l16;
                if (e < HD) op[e] = f2b(acc[i][j][r] * inv);
            }
        }
    }
}

// ---------------- depthwise conv k=3 + bias + GLU(silu); vectorized 8 ch/thread ----------------
// XCD-chunked block remap; g (row within batch) = (r0+nl) & (NSEQ-1). ybuf row = nl+rowoff.
__global__ __launch_bounds__(576)
void dwglu_kernel(const bf16* __restrict__ ybuf, const float* __restrict__ wdw,
                  const float* __restrict__ bdw, int r0, int rowoff, bf16* __restrict__ outg) {
    int bid = blockIdx.x;
    int nper = gridDim.x >> 3;                  // grid % 8 == 0
    int nl = (bid & 7) * nper + (bid >> 3);     // bijective XCD-chunk map
    int g = (r0 + nl) & (NSEQ - 1);             // row within its batch
    int c = threadIdx.x * 8;
    int cg = c + HIDC;
    size_t base = (size_t)(nl + rowoff) * HID2;
    const short* yb = (const short*)ybuf;
    short8 zr = {0, 0, 0, 0, 0, 0, 0, 0};
    bool hm = (g > 0), hp = (g < NSEQ - 1);
    short8 xm = hm ? *(const short8*)(yb + base - HID2 + c)  : zr;
    short8 x0 =      *(const short8*)(yb + base + c);
    short8 xp = hp ? *(const short8*)(yb + base + HID2 + c)  : zr;
    short8 gm = hm ? *(const short8*)(yb + base - HID2 + cg) : zr;
    short8 g0 =      *(const short8*)(yb + base + cg);
    short8 gp = hp ? *(const short8*)(yb + base + HID2 + cg) : zr;
    float wx[24], wg[24], bxv[8], bgv[8];
    #pragma unroll
    for (int t = 0; t < 6; t++) {
        *(floatx4*)&wx[t * 4] = *(const floatx4*)(wdw + (size_t)c * 3 + t * 4);
        *(floatx4*)&wg[t * 4] = *(const floatx4*)(wdw + (size_t)cg * 3 + t * 4);
    }
    *(floatx4*)&bxv[0] = *(const floatx4*)(bdw + c);
    *(floatx4*)&bxv[4] = *(const floatx4*)(bdw + c + 4);
    *(floatx4*)&bgv[0] = *(const floatx4*)(bdw + cg);
    *(floatx4*)&bgv[4] = *(const floatx4*)(bdw + cg + 4);
    short8 o;
    #pragma unroll
    for (int j = 0; j < 8; j++) {
        float a  = s2f(xm[j]) * wx[j * 3] + s2f(x0[j]) * wx[j * 3 + 1]
                 + s2f(xp[j]) * wx[j * 3 + 2] + bxv[j];
        float gg = s2f(gm[j]) * wg[j * 3] + s2f(g0[j]) * wg[j * 3 + 1]
                 + s2f(gp[j]) * wg[j * 3 + 2] + bgv[j];
        float sg = gg / (1.f + __expf(-gg));
        o[j] = f2s(a * sg);
    }
    *(short8*)((short*)outg + (size_t)nl * HIDC + c) = o;
}

extern "C" void kernel_launch(void* const* d_in, const int* in_sizes, int n_in,
                              void* d_out, int out_size, void* d_ws, size_t ws_size,
                              hipStream_t stream) {
    const float* h_in = (const float*)d_in[0];
    const float* temb = (const float*)d_in[1];
    const float* sst  = (const float*)d_in[2];
    const float* Wq = (const float*)d_in[3];   const float* bq_ = (const float*)d_in[4];
    const float* Wk = (const float*)d_in[5];   const float* bk_ = (const float*)d_in[6];
    const float* Wv = (const float*)d_in[7];   const float* bv_ = (const float*)d_in[8];
    const float* Wo = (const float*)d_in[9];   const float* bo_ = (const float*)d_in[10];
    const float* Winv = (const float*)d_in[11]; const float* binv = (const float*)d_in[12];
    const float* Wdw  = (const float*)d_in[13]; const float* bdw  = (const float*)d_in[14];
    const float* Wpt  = (const float*)d_in[15];
    float* out = (float*)d_out;

    const int WSMALL = DIMC * DIMC;       // 1,327,104
    const int WINVN  = HID2 * DIMC;
    const int WPTN   = DIMC * HIDC;

    char* basep = (char*)d_ws;
    size_t off = 0;
    auto alloc = [&](size_t bytes) -> char* {
        char* p = basep + off;
        off += (bytes + 255) & ~(size_t)255;
        return p;
    };
    // ---- fixed region (~51.5 MB) ----
    float* modsb = (float*)alloc((size_t)2 * 6 * DIMC * 4);
    float* kvb   = (float*)alloc((size_t)32 * KVH * 4);
    float* bqkv  = (float*)alloc((size_t)QKVN * 4);
    bf16* wib  = (bf16*)alloc((size_t)WINVN * 2);           // wib|wpb contiguous (cvt dstB)
    bf16* wpb  = (bf16*)alloc((size_t)WPTN * 2);
    bf16* trunk = (bf16*)alloc((size_t)NTOK * DIMC * 2);    // residual trunk (bf16)

    const size_t QKVB_B = (size_t)NTOK * QKVN * 2;          // 56,623,104
    const size_t BGLU2  = (size_t)NTOK * HIDC * 2;          // 75,497,472 == qkvb+bx
    const size_t BBIG_B = (size_t)NSEQ * HID2 * 2;          // 75,497,472 (per batch)
    const size_t WQKV_B = (size_t)3 * WSMALL * 2;           // 7,962,624
    const size_t WOB_B  = (size_t)WSMALL * 2;               // 2,654,208
    const size_t BX_B   = (size_t)NTOK * DIMC * 2;          // 18,874,368
    const size_t BGLU_B = (size_t)NSEQ * HIDC * 2;          // 37,748,736

    // tiers: 0m merged FFN (R = bglu 75.5 | bbig 151) = 226.5 MB overlay
    //        0  per-batch bbig (R = bglu 75.5 | bbig 75.5) = 151 MB overlay (known to fit)
    //        1/2 fallbacks. Overlay ledger (0m/0): qkvb=[0,56.6) bx=[56.6,75.5);
    //        wqkv|wob live inside bbig region (dead before FFN writes it).
    bool t0m = (ws_size >= off + BGLU2 + 2 * BBIG_B + 1024);
    bool t0  = !t0m && (ws_size >= off + BGLU2 + BBIG_B + 1024);

    bf16 *qkvb, *bx, *wqkv, *wob;
    char* R;
    bool t1 = false;
    if (t0m || t0) {
        R = alloc(BGLU2 + (t0m ? 2 * BBIG_B : BBIG_B));
        qkvb = (bf16*)R;
        bx   = (bf16*)(R + QKVB_B);
        wqkv = (bf16*)(R + BGLU2);
        wob  = (bf16*)(R + BGLU2 + WQKV_B);
    } else {
        wqkv = (bf16*)alloc(WQKV_B);                        // wqkv|wob contiguous (cvt dstA)
        wob  = (bf16*)alloc(WOB_B);
        bx   = (bf16*)alloc(BX_B);
        t1 = (ws_size >= off + BGLU_B + BBIG_B + 1024);
        R = alloc(t1 ? (BGLU_B + BBIG_B) : (size_t)61341696);
        qkvb = (bf16*)R;
    }

    // setup: weight cvt + mods + bias3 + kv zero (one kernel)
    setup_kernel<<<21452, 256, 0, stream>>>(Wq, Wk, Wv, Wo, Winv, Wpt, wqkv, wib,
                                            sst, temb, modsb, bq_, bk_, bv_, bqkv, kvb);
    rmsmod_kernel<float><<<NTOK, 256, 0, stream>>>(h_in, modsb, 0, 1, bx);

    // fused QKV: (8192 x 1152) @ (3456 x 1152)^T -> qkvb
    gemm_kernel<0, bf16><<<dim3(NTOK / 128, QKVN / 128), 256, 0, stream>>>(
        bx, wqkv, bqkv, nullptr, 0, 0, nullptr, qkvb, QKVN, DIMC, DIMC, 0, 0, 1 << 30);

    // linear attention: MFMA KV (atomic accumulate) + MFMA out
    attn_kv_kernel<<<dim3(KV_CHUNKS, 16, 2), 256, 0, stream>>>(qkvb, kvb);
    attn_out_kernel<<<dim3(32, 16, 2), 256, 0, stream>>>(qkvb, kvb, bx);
    // Wo + gate_msa*attn + resid(h_in) -> trunk
    gemm_kernel<2, bf16><<<dim3(NTOK / 128, DIMC / 128), 256, 0, stream>>>(
        bx, wob, bo_, modsb, 2, 0, h_in, trunk, DIMC, DIMC, DIMC, 0, 0, 1 << 30);
    // y = rms(trunk)*(1+scale_mlp)+shift_mlp -> bx
    rmsmod_kernel<bf16><<<NTOK, 256, 0, stream>>>(trunk, modsb, 3, 4, bx);

    if (t0m) {
        // ---- merged-batch FFN: one W_inv (4608 blocks = 18/CU), one dwglu, one MODE-6 W_pt ----
        bf16* bglu = (bf16*)R;                              // 8192 x 4608
        bf16* bbig = (bf16*)(R + BGLU2);                    // 8192 x 9216 (overwrites wqkv/wob, dead)
        gemm_kernel<3, bf16><<<dim3(NTOK / 128, HID2 / 128), 256, 0, stream>>>(
            bx, wib, binv, nullptr, 0, 0, nullptr, bbig, HID2, DIMC, DIMC, 0, 0, 1 << 30);
        // dwglu merged (overwrites qkvb+bx, both dead: W_inv already consumed bx)
        dwglu_kernel<<<dim3(NTOK), 576, 0, stream>>>(bbig, Wdw, bdw, 0, 0, bglu);
        gemm_kernel<6, float><<<dim3(NTOK / 128, DIMC / 128), 256, 0, stream>>>(
            bglu, wpb, nullptr, modsb, 5, 0, (const float*)trunk, out, DIMC, HIDC, HIDC,
            0, 0, 1 << 30);
    } else if (t0) {
        // ---- round-10 path: per-batch W_inv/dwglu into merged bglu, one MODE-6 W_pt ----
        bf16* bglu = (bf16*)R;
        bf16* bbig = (bf16*)(R + BGLU2);
        for (int b = 0; b < 2; ++b) {
            const bf16* Ainv = bx + (size_t)b * NSEQ * DIMC;
            gemm_kernel<3, bf16><<<dim3(NSEQ / 128, HID2 / 128), 256, 0, stream>>>(
                Ainv, wib, binv, nullptr, 0, 0, nullptr, bbig, HID2, DIMC, DIMC, 0, 0, 1 << 30);
            dwglu_kernel<<<dim3(NSEQ), 576, 0, stream>>>(
                bbig, Wdw, bdw, 0, 0, bglu + (size_t)b * NSEQ * HIDC);
        }
        gemm_kernel<6, float><<<dim3(NTOK / 128, DIMC / 128), 256, 0, stream>>>(
            bglu, wpb, nullptr, modsb, 5, 0, (const float*)trunk, out, DIMC, HIDC, HIDC,
            0, 0, 1 << 30);
    } else if (t1) {
        // ---- per-batch FFN with split-K + reduce (round-8 path) ----
        bf16*  bglu = (bf16*)R;
        bf16*  bbig = (bf16*)(R + BGLU_B);
        float* partials = (float*)(R + BGLU_B);             // aliases bbig (dead after dwglu)
        for (int b = 0; b < 2; ++b) {
            const bf16* Ainv = bx + (size_t)b * NSEQ * DIMC;
            gemm_kernel<3, bf16><<<dim3(NSEQ / 128, HID2 / 128), 256, 0, stream>>>(
                Ainv, wib, binv, nullptr, 0, 0, nullptr, bbig, HID2, DIMC, DIMC, 0, 0, 1 << 30);
            dwglu_kernel<<<dim3(NSEQ), 576, 0, stream>>>(bbig, Wdw, bdw, 0, 0, bglu);
            gemm_kernel<5, float><<<dim3(32, DIMC / 128, 2), 256, 0, stream>>>(
                bglu, wpb, nullptr, nullptr, 0, 0, nullptr, partials, DIMC, HIDC, HIDC / 2,
                PZB, 0, 1 << 30);
            reduce_kernel<2><<<(int)(PZB / 1024), 256, 0, stream>>>(partials, trunk, modsb, b, 0,
                                                                    PZB, out);
        }
    } else {
        // ---- fallback: 2048-row chunks with 128-row halo ----
        bf16*  bglu_c   = (bf16*)R;                         // 2048 x 4608 bf16
        bf16*  bbig_c   = (bf16*)(R + (size_t)18874368);    // 2304 x 9216 bf16
        float* partials = (float*)(R + (size_t)18874368);   // 4 x 2048 x 1152 f32 (aliases bbig)
        for (int b = 0; b < 2; ++b) {
            for (int c = 0; c < 2; ++c) {
                int r0 = c * 2048;
                int lo = (c == 0) ? 1 : 0;
                int hi = (c == 0) ? 18 : 17;
                const bf16* Ainv = bx + ((size_t)(b * NSEQ + r0)) * DIMC - (size_t)128 * DIMC;
                gemm_kernel<3, bf16><<<dim3(18, HID2 / 128), 256, 0, stream>>>(
                    Ainv, wib, binv, nullptr, 0, 0, nullptr, bbig_c, HID2, DIMC, DIMC, 0, lo, hi);
                dwglu_kernel<<<dim3(2048), 576, 0, stream>>>(bbig_c, Wdw, bdw, r0, 128, bglu_c);
                gemm_kernel<5, float><<<dim3(16, DIMC / 128, 4), 256, 0, stream>>>(
                    bglu_c, wpb, nullptr, nullptr, 0, 0, nullptr, partials, DIMC, HIDC, HIDC / 4,
                    PZ, 0, 1 << 30);
                reduce_kernel<4><<<(int)(PZ / 1024), 256, 0, stream>>>(partials, trunk, modsb, b,
                                                                       r0, PZ, out);
            }
        }
    }
}

// Round 12
// 742.195 us; speedup vs baseline: 1.0497x; 1.0497x over previous
//
#include <hip/hip_runtime.h>
#include <hip/hip_bf16.h>

typedef __hip_bfloat16 bf16;
typedef short short8 __attribute__((ext_vector_type(8)));   // 8 bf16 bit-patterns (4 VGPRs)
typedef short short4v __attribute__((ext_vector_type(4)));
typedef float floatx4 __attribute__((ext_vector_type(4)));
typedef int int4v __attribute__((ext_vector_type(4)));

#define DIMC 1152
#define NTOK 8192    // B*N
#define NSEQ 4096
#define HD 72
#define HDP 73       // HD + 1 (padded-ones value column)
#define HIDC 4608
#define HID2 9216
#define QKVN 3456    // 3*DIMC
#define KVH (HD * HDP)            // 5256 per (b,h)
#define PZ ((size_t)2048 * DIMC)  // split-K partial plane (2048-row chunk, fallback)
#define PZB ((size_t)4096 * DIMC) // split-K partial plane (per-batch fallback)

// attn_kv MFMA geometry
#define DP 96        // padded d/e extent (6 x 16)
#define KVNT 128     // tokens per LDS tile
#define KV_NITER 2   // LDS tiles per block
#define KV_CHUNKS 16 // chunks per batch (16 * 256 = 4096 tokens)

__device__ __forceinline__ float b2f(bf16 x) { return __bfloat162float(x); }
__device__ __forceinline__ bf16 f2b(float x) { return __float2bfloat16(x); }
__device__ __forceinline__ void st(float* p, float v) { *p = v; }
__device__ __forceinline__ void st(bf16* p, float v)  { *p = f2b(v); }
__device__ __forceinline__ float tf(float x) { return x; }
__device__ __forceinline__ float tf(bf16 x)  { return __bfloat162float(x); }
__device__ __forceinline__ float s2f(short s) {
    unsigned int u = ((unsigned int)(unsigned short)s) << 16;
    return __uint_as_float(u);
}
__device__ __forceinline__ short f2s(float f) {
    bf16 h = f2b(f);
    return *reinterpret_cast<short*>(&h);
}

// async global->LDS DMA, 16B per lane. LDS dest is wave-uniform base + lane*16.
__device__ __forceinline__ void gload_lds16(const bf16* g, short* l) {
    __builtin_amdgcn_global_load_lds(
        (const __attribute__((address_space(1))) void*)g,
        (__attribute__((address_space(3))) void*)l, 16, 0, 0);
}

// ---------------- setup: weight cvt (f32->bf16, two dst regions) + mods + bias3 ----------------
// blocks [0,20736): cvt. dstA (f4 [0,1327104)): Wq|Wk|Wv|Wo. dstB: Winv|Wpt.
// blocks [20736,20795): i<13824 mods = sst+temb; then bias3 concat.
__global__ void setup_kernel(const float* __restrict__ s0, const float* __restrict__ s1,
                             const float* __restrict__ s2, const float* __restrict__ s3,
                             const float* __restrict__ s4, const float* __restrict__ s5,
                             bf16* __restrict__ dstA, bf16* __restrict__ dstB,
                             const float* __restrict__ sst, const float* __restrict__ temb,
                             float* __restrict__ mods, const float* __restrict__ ba,
                             const float* __restrict__ bb, const float* __restrict__ bc,
                             float* __restrict__ bq) {
    int gb = blockIdx.x;
    if (gb < 20736) {
        int i = gb * 256 + threadIdx.x;   // float4 index, total 5308416
        if (i >= 5308416) return;
        const float* src; int base, ib; bf16* dst;
        if (i < 1327104) {
            dst = dstA; ib = i;
            if (i < 331776)      { src = s0; base = 0; }
            else if (i < 663552) { src = s1; base = 331776; }
            else if (i < 995328) { src = s2; base = 663552; }
            else                 { src = s3; base = 995328; }
        } else {
            dst = dstB; ib = i - 1327104;
            if (i < 3981312)     { src = s4; base = 1327104; }
            else                 { src = s5; base = 3981312; }
        }
        floatx4 v = ((const floatx4*)src)[i - base];
        bf16* o = dst + (size_t)ib * 4;
        o[0] = f2b(v[0]); o[1] = f2b(v[1]); o[2] = f2b(v[2]); o[3] = f2b(v[3]);
    } else {
        int i = (gb - 20736) * 256 + threadIdx.x;
        if (i < 13824) {
            mods[i] = sst[i % (6 * DIMC)] + temb[i];
        } else if (i < 13824 + DIMC) {
            int j = i - 13824;
            bq[j] = ba[j]; bq[j + DIMC] = bb[j]; bq[j + 2 * DIMC] = bc[j];
        }
    }
}

// ---------------- x = rms(h)*(1+scale)+shift; out bf16. Vectorized 8/thread, single read ----------------
template<typename T>
__global__ void rmsmod_kernel(const T* __restrict__ h, const float* __restrict__ mods,
                              int shift_idx, int scale_idx, bf16* __restrict__ xout) {
    int token = blockIdx.x;            // 0..8191
    int b = token >> 12;
    int tid = threadIdx.x;
    int wave = tid >> 6, lane = tid & 63;
    const T* hp = h + (size_t)token * DIMC;

    float v[8];
    float s = 0.f;
    if (tid < 144) {                   // 144*8 = 1152
        if constexpr (sizeof(T) == 4) {
            floatx4 a = *(const floatx4*)((const float*)hp + tid * 8);
            floatx4 c = *(const floatx4*)((const float*)hp + tid * 8 + 4);
            v[0]=a[0]; v[1]=a[1]; v[2]=a[2]; v[3]=a[3];
            v[4]=c[0]; v[5]=c[1]; v[6]=c[2]; v[7]=c[3];
        } else {
            short8 a = *(const short8*)((const short*)hp + tid * 8);
            #pragma unroll
            for (int j = 0; j < 8; j++) v[j] = s2f(a[j]);
        }
        #pragma unroll
        for (int j = 0; j < 8; j++) s += v[j] * v[j];
    }
    #pragma unroll
    for (int off = 32; off > 0; off >>= 1) s += __shfl_down(s, off);
    __shared__ float wsum[4];
    if (lane == 0) wsum[wave] = s;
    __syncthreads();
    float tot = wsum[0] + wsum[1] + wsum[2] + wsum[3];
    float r = rsqrtf(tot / (float)DIMC + 1e-6f);

    if (tid < 144) {
        const float* sh = mods + (size_t)(b * 6 + shift_idx) * DIMC + tid * 8;
        const float* sc = mods + (size_t)(b * 6 + scale_idx) * DIMC + tid * 8;
        floatx4 sh0 = *(const floatx4*)sh, sh1 = *(const floatx4*)(sh + 4);
        floatx4 sc0 = *(const floatx4*)sc, sc1 = *(const floatx4*)(sc + 4);
        short8 o;
        o[0] = f2s(v[0] * r * (1.f + sc0[0]) + sh0[0]);
        o[1] = f2s(v[1] * r * (1.f + sc0[1]) + sh0[1]);
        o[2] = f2s(v[2] * r * (1.f + sc0[2]) + sh0[2]);
        o[3] = f2s(v[3] * r * (1.f + sc0[3]) + sh0[3]);
        o[4] = f2s(v[4] * r * (1.f + sc1[0]) + sh1[0]);
        o[5] = f2s(v[5] * r * (1.f + sc1[1]) + sh1[1]);
        o[6] = f2s(v[6] * r * (1.f + sc1[2]) + sh1[2]);
        o[7] = f2s(v[7] * r * (1.f + sc1[3]) + sh1[3]);
        *(short8*)((short*)xout + (size_t)token * DIMC + tid * 8) = o;
    }
}

// ---------------- 128x128 MFMA GEMM (m97-structure, BK=64, both-sides swizzle) ----------------
// MODE 0: QKV fused: acc+bias, relu iff col<2304      -> bf16 (N=3456)
// MODE 2: gate*(acc+bias)+resid(f32)                   -> bf16 trunk
// MODE 3: silu(acc+bias)                               -> bf16
// MODE 5: raw partial acc (split-K via blockIdx.z)     -> f32 at zstride*z
// MODE 6: trunk(bf16 via resid) + mods[gate]*acc       -> f32 (fused W_pt + reduce, full K)
template<int MODE, typename OT>
__global__ __launch_bounds__(256, 2)
void gemm_kernel(const bf16* __restrict__ A, const bf16* __restrict__ W,
                 const float* __restrict__ bias, const float* __restrict__ mods,
                 int gate_idx, int m_off, const float* __restrict__ resid,
                 OT* __restrict__ out, int N, int Kfull, int Klen,
                 size_t zstride, int bm_lo, int bm_hi) {
    const int bm = blockIdx.x;
    if (bm < bm_lo || bm >= bm_hi) return;
    const int koff = blockIdx.z * Klen;
    __shared__ __align__(16) short As[128 * 64];   // [128 rows][64 k] linear (row=128B)
    __shared__ __align__(16) short Bs[128 * 64];
    const int tid = threadIdx.x;
    const int wave = tid >> 6;
    const int lane = tid & 63;
    const int quad = lane >> 4;
    const int l16 = lane & 15;
    const int wm = (wave & 1) * 64;
    const int wn = (wave >> 1) * 64;
    const int bn = blockIdx.y;

    floatx4 acc[4][4];
    #pragma unroll
    for (int i = 0; i < 4; i++)
        #pragma unroll
        for (int j = 0; j < 4; j++)
            #pragma unroll
            for (int r = 0; r < 4; r++) acc[i][j][r] = 0.0f;

    const int lrow8 = lane >> 3;                     // row within 8-row group == row&7
    const int scol = ((lane & 7) ^ lrow8) * 8;       // pre-swizzled source col (elems)
    const bf16* gA = A + (size_t)(bm * 128 + wave * 8 + lrow8) * Kfull + koff + scol;
    const bf16* gB = W + (size_t)(bn * 128 + wave * 8 + lrow8) * Kfull + koff + scol;
    short* lA = &As[wave * 512];
    short* lB = &Bs[wave * 512];
    const size_t rstep = (size_t)32 * Kfull;         // 32 rows between issues

    for (int k0 = 0; k0 < Klen; k0 += 64) {
        __syncthreads();
        #pragma unroll
        for (int j = 0; j < 4; j++) gload_lds16(gA + j * rstep + k0, lA + j * 2048);
        #pragma unroll
        for (int j = 0; j < 4; j++) gload_lds16(gB + j * rstep + k0, lB + j * 2048);
        __syncthreads();
        short8 af[2][4], bfr[2][4];
        #pragma unroll
        for (int i = 0; i < 4; i++) {
            const int ra = wm + i * 16 + l16;
            const int rb = wn + i * 16 + l16;
            #pragma unroll
            for (int kk = 0; kk < 2; kk++) {
                af[kk][i]  = *(const short8*)&As[ra * 64 + (((kk * 4 + quad) ^ (ra & 7)) * 8)];
                bfr[kk][i] = *(const short8*)&Bs[rb * 64 + (((kk * 4 + quad) ^ (rb & 7)) * 8)];
            }
        }
        #pragma unroll
        for (int kk = 0; kk < 2; kk++)
            #pragma unroll
            for (int i = 0; i < 4; i++)
                #pragma unroll
                for (int j = 0; j < 4; j++)
                    acc[i][j] = __builtin_amdgcn_mfma_f32_16x16x32_bf16(af[kk][i], bfr[kk][j], acc[i][j], 0, 0, 0);
    }

    #pragma unroll
    for (int i = 0; i < 4; i++) {
        #pragma unroll
        for (int j = 0; j < 4; j++) {
            const int col = bn * 128 + wn + j * 16 + l16;
            #pragma unroll
            for (int r = 0; r < 4; r++) {
                const int m = bm * 128 + wm + i * 16 + quad * 4 + r;
                float v = acc[i][j][r];
                float o;
                if (MODE == 0) {
                    o = v + bias[col];
                    if (col < 2 * DIMC) o = fmaxf(o, 0.f);
                } else if (MODE == 2) {
                    int b = (m + m_off) >> 12;
                    o = mods[(size_t)(b * 6 + gate_idx) * DIMC + col] * (v + bias[col])
                        + resid[(size_t)m * DIMC + col];
                } else if (MODE == 3) {
                    float sv = v + bias[col];
                    o = sv / (1.f + __expf(-sv));
                } else if (MODE == 6) {
                    const bf16* tr = (const bf16*)resid;         // trunk (bf16)
                    int b = m >> 12;
                    o = tf(tr[(size_t)m * DIMC + col])
                        + mods[(size_t)(b * 6 + gate_idx) * DIMC + col] * v;
                } else {  // MODE 5: raw partial
                    o = v;
                }
                st(&out[zstride * blockIdx.z + (size_t)m * N + col], o);
            }
        }
    }
}

// ---------------- split-K reduce (vectorized 4/thread): out = trunk + gate_mlp * sum(planes) ----------------
template<int NP>
__global__ void reduce_kernel(const float* __restrict__ part, const bf16* __restrict__ trunk,
                              const float* __restrict__ mods, int b, int r0, size_t pstride,
                              float* __restrict__ out) {
    int i4 = (blockIdx.x * 256 + threadIdx.x) * 4;
    int col = i4 % DIMC;                               // 4 cols contiguous (DIMC % 4 == 0)
    floatx4 s = *(const floatx4*)(part + i4);
    #pragma unroll
    for (int p = 1; p < NP; ++p) {
        floatx4 t = *(const floatx4*)(part + (size_t)p * pstride + i4);
        s[0] += t[0]; s[1] += t[1]; s[2] += t[2]; s[3] += t[3];
    }
    size_t gidx = ((size_t)b * NSEQ + r0) * DIMC + i4;
    short4v tr = *(const short4v*)((const short*)trunk + gidx);
    floatx4 g = *(const floatx4*)(mods + (size_t)(b * 6 + 5) * DIMC + col);
    floatx4 o;
    #pragma unroll
    for (int j = 0; j < 4; ++j) o[j] = s2f(tr[j]) + g[j] * s[j];
    *(floatx4*)(out + gidx) = o;
}

// ---------------- attention phase A (MFMA): KV[d][e] = sum_n k[n,d]*vpad[n,e] ----------------
// Per-chunk partial stores (no atomics — measured faster than atomicAdd, rounds 10 vs 11).
__device__ __forceinline__ int kvaddr(int row, int n) {   // short index
    return row * KVNT + ((((n >> 3) ^ (row & 7))) << 3) + (n & 7);
}

__global__ __launch_bounds__(256, 3)
void attn_kv_kernel(const bf16* __restrict__ qkv, float* __restrict__ part) {
    const int chunk = blockIdx.x;   // 16 chunks of 256 tokens
    const int h = blockIdx.y;       // 16 heads
    const int b = blockIdx.z;       // 2 batches
    __shared__ __align__(16) short kl[DP * KVNT];   // 24 KB
    __shared__ __align__(16) short vl[DP * KVNT];   // 24 KB
    const int tid = threadIdx.x;
    const int wave = tid >> 6, lane = tid & 63;
    const int quad = lane >> 4, l16 = lane & 15;
    const int wd = (wave & 1) * 48;     // d-half
    const int we = (wave >> 1) * 48;    // e-half

    for (int i = tid; i < 24 * KVNT; i += 256) {
        kl[72 * KVNT + i] = 0;
        vl[72 * KVNT + i] = (i < KVNT) ? (short)0x3F80 : (short)0;   // row 72 = bf16 1.0
    }

    floatx4 acc[3][3];
    #pragma unroll
    for (int i = 0; i < 3; i++)
        #pragma unroll
        for (int j = 0; j < 3; j++)
            #pragma unroll
            for (int r = 0; r < 4; r++) acc[i][j][r] = 0.0f;

    const size_t tok0 = (size_t)b * NSEQ + (size_t)chunk * (KVNT * KV_NITER);
    for (int it = 0; it < KV_NITER; ++it) {
        __syncthreads();
        const short* rb = (const short*)qkv + (tok0 + (size_t)it * KVNT) * QKVN + h * HD;
        #pragma unroll
        for (int p = 0; p < 5; ++p) {
            int idx = p * 256 + tid;
            int o = idx >> 7, n = idx & 127;
            if (o < 9) {
                const short* g = rb + (size_t)n * QKVN + o * 8;
                short8 kk = *(const short8*)(g + DIMC);
                short8 vv = *(const short8*)(g + 2 * DIMC);
                #pragma unroll
                for (int j = 0; j < 8; ++j) {
                    kl[kvaddr(o * 8 + j, n)] = kk[j];
                    vl[kvaddr(o * 8 + j, n)] = vv[j];
                }
            }
        }
        __syncthreads();
        #pragma unroll
        for (int ks = 0; ks < 4; ++ks) {
            const int nb = ks * 32 + quad * 8;
            short8 af[3], bfv[3];
            #pragma unroll
            for (int i = 0; i < 3; ++i) {
                const int ra = wd + i * 16 + l16;
                const int rbn = we + i * 16 + l16;
                af[i]  = *(const short8*)&kl[ra * KVNT + ((((nb >> 3) ^ (ra & 7))) << 3)];
                bfv[i] = *(const short8*)&vl[rbn * KVNT + ((((nb >> 3) ^ (rbn & 7))) << 3)];
            }
            #pragma unroll
            for (int i = 0; i < 3; ++i)
                #pragma unroll
                for (int j = 0; j < 3; ++j)
                    acc[i][j] = __builtin_amdgcn_mfma_f32_16x16x32_bf16(af[i], bfv[j], acc[i][j], 0, 0, 0);
        }
    }

    float* op = part + ((size_t)((b * 16 + h) * KV_CHUNKS + chunk)) * KVH;
    #pragma unroll
    for (int i = 0; i < 3; ++i) {
        const int dbase = wd + i * 16 + quad * 4;
        #pragma unroll
        for (int j = 0; j < 3; ++j) {
            const int e = we + j * 16 + l16;
            if (e < HDP) {
                #pragma unroll
                for (int r = 0; r < 4; ++r) {
                    const int d = dbase + r;
                    if (d < HD) op[d * HDP + e] = acc[i][j][r];
                }
            }
        }
    }
}

// ---------------- kv partial reduce ----------------
__global__ void kvred_kernel(const float* __restrict__ part, float* __restrict__ kvout) {
    int i = blockIdx.x * 256 + threadIdx.x;
    if (i >= 32 * KVH) return;
    int bh = i / KVH, cell = i - bh * KVH;
    const float* p = part + ((size_t)bh * KV_CHUNKS) * KVH + cell;
    float s = 0.f;
    #pragma unroll
    for (int c = 0; c < KV_CHUNKS; ++c) s += p[(size_t)c * KVH];
    kvout[i] = s;
}

// ---------------- attention phase B (MFMA): Out[n][e] = Q[n][:]·KVT[e][:]; out = num/den ----------------
__global__ __launch_bounds__(256, 2)
void attn_out_kernel(const bf16* __restrict__ qkv, const float* __restrict__ kv,
                     bf16* __restrict__ outa) {
    const int chunk = blockIdx.x;   // 32 chunks of 128 tokens
    const int h = blockIdx.y;       // 16 heads
    const int b = blockIdx.z;       // 2 batches
    __shared__ __align__(16) short ql[128 * 128];   // 32 KB
    __shared__ __align__(16) short kvt[80 * 128];   // 20 KB
    const int tid = threadIdx.x;
    const int wave = tid >> 6, lane = tid & 63;
    const int quad = lane >> 4, l16 = lane & 15;
    const int wm = wave * 32;       // 2 M-frags (32 token-rows) per wave

    // stage Q: 128 rows x 16 slots = 2048 tasks; slots 9..15 zero (d >= 72)
    const short* qbase = (const short*)qkv + ((size_t)(b * NSEQ) + (size_t)chunk * 128) * QKVN + h * HD;
    #pragma unroll
    for (int t = 0; t < 8; ++t) {
        int idx = t * 256 + tid;
        int o = idx >> 7, n = idx & 127;
        short8 vv = {0, 0, 0, 0, 0, 0, 0, 0};
        if (o < 9) vv = *(const short8*)(qbase + (size_t)n * QKVN + o * 8);
        *(short8*)&ql[n * 128 + ((o ^ (n & 7)) << 3)] = vv;
    }
    // stage KVT: 80 e-rows x 16 slots = 1280 tasks; kv is f32 [d*73+e] per (b,h)
    const float* kp = kv + (size_t)(b * 16 + h) * KVH;
    #pragma unroll
    for (int t = 0; t < 5; ++t) {
        int idx = t * 256 + tid;
        int o = idx / 80, e = idx - (idx / 80) * 80;
        short8 vv = {0, 0, 0, 0, 0, 0, 0, 0};
        if (e < HDP && o < 9) {
            #pragma unroll
            for (int j = 0; j < 8; ++j) {
                int d = o * 8 + j;
                if (d < HD) vv[j] = f2s(kp[(size_t)d * HDP + e]);
            }
        }
        *(short8*)&kvt[e * 128 + ((o ^ (e & 7)) << 3)] = vv;
    }
    __syncthreads();

    floatx4 acc[2][5];
    #pragma unroll
    for (int i = 0; i < 2; ++i)
        #pragma unroll
        for (int j = 0; j < 5; ++j)
            #pragma unroll
            for (int r = 0; r < 4; ++r) acc[i][j][r] = 0.0f;

    #pragma unroll
    for (int kk = 0; kk < 3; ++kk) {
        const int s = kk * 4 + quad;                 // k-slot 0..11 (d = s*8..s*8+7)
        short8 af[2];
        #pragma unroll
        for (int i = 0; i < 2; ++i) {
            const int ra = wm + i * 16 + l16;
            af[i] = *(const short8*)&ql[ra * 128 + ((s ^ (ra & 7)) << 3)];
        }
        #pragma unroll
        for (int j = 0; j < 5; ++j) {
            const int rb = j * 16 + l16;
            short8 bfv = *(const short8*)&kvt[rb * 128 + ((s ^ (rb & 7)) << 3)];
            #pragma unroll
            for (int i = 0; i < 2; ++i)
                acc[i][j] = __builtin_amdgcn_mfma_f32_16x16x32_bf16(af[i], bfv, acc[i][j], 0, 0, 0);
        }
    }

    // epilogue: den[row] = output col 72 = N-frag 4, l16 == 8; shfl-broadcast within quad
    #pragma unroll
    for (int i = 0; i < 2; ++i) {
        #pragma unroll
        for (int r = 0; r < 4; ++r) {
            float den = __shfl(acc[i][4][r], (lane & 48) | 8);
            float inv = 1.0f / (den + 1e-15f);
            const int m = wm + i * 16 + quad * 4 + r;        // token within chunk
            bf16* op = outa + ((size_t)(b * NSEQ) + (size_t)chunk * 128 + m) * DIMC + h * HD;
            #pragma unroll
            for (int j = 0; j < 5; ++j) {
                const int e = j * 16 + l16;
                if (e < HD) op[e] = f2b(acc[i][j][r] * inv);
            }
        }
    }
}

// ---------------- depthwise conv k=3 + bias + GLU(silu); vectorized 8 ch/thread ----------------
// XCD-chunked block remap; g (row within batch) = (r0+nl) & (NSEQ-1). ybuf row = nl+rowoff.
__global__ __launch_bounds__(576)
void dwglu_kernel(const bf16* __restrict__ ybuf, const float* __restrict__ wdw,
                  const float* __restrict__ bdw, int r0, int rowoff, bf16* __restrict__ outg) {
    int bid = blockIdx.x;
    int nper = gridDim.x >> 3;                  // grid % 8 == 0
    int nl = (bid & 7) * nper + (bid >> 3);     // bijective XCD-chunk map
    int g = (r0 + nl) & (NSEQ - 1);             // row within its batch
    int c = threadIdx.x * 8;
    int cg = c + HIDC;
    size_t base = (size_t)(nl + rowoff) * HID2;
    const short* yb = (const short*)ybuf;
    short8 zr = {0, 0, 0, 0, 0, 0, 0, 0};
    bool hm = (g > 0), hp = (g < NSEQ - 1);
    short8 xm = hm ? *(const short8*)(yb + base - HID2 + c)  : zr;
    short8 x0 =      *(const short8*)(yb + base + c);
    short8 xp = hp ? *(const short8*)(yb + base + HID2 + c)  : zr;
    short8 gm = hm ? *(const short8*)(yb + base - HID2 + cg) : zr;
    short8 g0 =      *(const short8*)(yb + base + cg);
    short8 gp = hp ? *(const short8*)(yb + base + HID2 + cg) : zr;
    float wx[24], wg[24], bxv[8], bgv[8];
    #pragma unroll
    for (int t = 0; t < 6; t++) {
        *(floatx4*)&wx[t * 4] = *(const floatx4*)(wdw + (size_t)c * 3 + t * 4);
        *(floatx4*)&wg[t * 4] = *(const floatx4*)(wdw + (size_t)cg * 3 + t * 4);
    }
    *(floatx4*)&bxv[0] = *(const floatx4*)(bdw + c);
    *(floatx4*)&bxv[4] = *(const floatx4*)(bdw + c + 4);
    *(floatx4*)&bgv[0] = *(const floatx4*)(bdw + cg);
    *(floatx4*)&bgv[4] = *(const floatx4*)(bdw + cg + 4);
    short8 o;
    #pragma unroll
    for (int j = 0; j < 8; j++) {
        float a  = s2f(xm[j]) * wx[j * 3] + s2f(x0[j]) * wx[j * 3 + 1]
                 + s2f(xp[j]) * wx[j * 3 + 2] + bxv[j];
        float gg = s2f(gm[j]) * wg[j * 3] + s2f(g0[j]) * wg[j * 3 + 1]
                 + s2f(gp[j]) * wg[j * 3 + 2] + bgv[j];
        float sg = gg / (1.f + __expf(-gg));
        o[j] = f2s(a * sg);
    }
    *(short8*)((short*)outg + (size_t)nl * HIDC + c) = o;
}

extern "C" void kernel_launch(void* const* d_in, const int* in_sizes, int n_in,
                              void* d_out, int out_size, void* d_ws, size_t ws_size,
                              hipStream_t stream) {
    const float* h_in = (const float*)d_in[0];
    const float* temb = (const float*)d_in[1];
    const float* sst  = (const float*)d_in[2];
    const float* Wq = (const float*)d_in[3];   const float* bq_ = (const float*)d_in[4];
    const float* Wk = (const float*)d_in[5];   const float* bk_ = (const float*)d_in[6];
    const float* Wv = (const float*)d_in[7];   const float* bv_ = (const float*)d_in[8];
    const float* Wo = (const float*)d_in[9];   const float* bo_ = (const float*)d_in[10];
    const float* Winv = (const float*)d_in[11]; const float* binv = (const float*)d_in[12];
    const float* Wdw  = (const float*)d_in[13]; const float* bdw  = (const float*)d_in[14];
    const float* Wpt  = (const float*)d_in[15];
    float* out = (float*)d_out;

    const int WSMALL = DIMC * DIMC;       // 1,327,104
    const int WINVN  = HID2 * DIMC;
    const int WPTN   = DIMC * HIDC;

    char* basep = (char*)d_ws;
    size_t off = 0;
    auto alloc = [&](size_t bytes) -> char* {
        char* p = basep + off;
        off += (bytes + 255) & ~(size_t)255;
        return p;
    };
    // ---- fixed region ----
    float* modsb = (float*)alloc((size_t)2 * 6 * DIMC * 4);
    float* kvb   = (float*)alloc((size_t)32 * KVH * 4);
    float* bqkv  = (float*)alloc((size_t)QKVN * 4);
    bf16* wib  = (bf16*)alloc((size_t)WINVN * 2);           // wib|wpb contiguous (cvt dstB)
    bf16* wpb  = (bf16*)alloc((size_t)WPTN * 2);
    bf16* trunk = (bf16*)alloc((size_t)NTOK * DIMC * 2);    // residual trunk (bf16)

    const size_t QKVB_B  = (size_t)NTOK * QKVN * 2;         // 56,623,104
    const size_t BX_B    = (size_t)NTOK * DIMC * 2;         // 18,874,368
    const size_t BGLU2   = (size_t)NTOK * HIDC * 2;         // 75,497,472 == QKVB_B + BX_B
    const size_t BBIG_B  = (size_t)NSEQ * HID2 * 2;         // 75,497,472 (per batch)
    const size_t KVPART_B = (size_t)32 * KV_CHUNKS * KVH * 4; // 10,764,288
    const size_t WQKV_B  = (size_t)3 * WSMALL * 2;          // 7,962,624
    const size_t WOB_B   = (size_t)WSMALL * 2;              // 2,654,208
    const size_t BGLU_B  = (size_t)NSEQ * HIDC * 2;         // 37,748,736

    // tier 0 (round-10 measured-best, ~203 MB): R = [bglu_merged 75.5 | bbig_per_batch 75.5]
    //   overlay ledger: qkvb=[0,56.6) bx=[56.6,75.5) | kvpart/wqkv/wob inside bbig (dead pre-FFN)
    bool tier0 = (ws_size >= off + BGLU2 + BBIG_B + 1024);

    bf16 *qkvb, *bx, *wqkv, *wob;
    float* kvpart;
    char* R;
    bool tier1 = false;
    if (tier0) {
        R = alloc(BGLU2 + BBIG_B);
        qkvb   = (bf16*)R;
        bx     = (bf16*)(R + QKVB_B);
        kvpart = (float*)(R + BGLU2);
        wqkv   = (bf16*)(R + BGLU2 + KVPART_B);
        wob    = (bf16*)(R + BGLU2 + KVPART_B + WQKV_B);
    } else {
        kvpart = (float*)alloc(KVPART_B);
        wqkv   = (bf16*)alloc(WQKV_B);                      // wqkv|wob contiguous (cvt dstA)
        wob    = (bf16*)alloc(WOB_B);
        bx     = (bf16*)alloc(BX_B);
        tier1 = (ws_size >= off + BGLU_B + BBIG_B + 1024);
        R = alloc(tier1 ? (BGLU_B + BBIG_B) : (size_t)61341696);
        qkvb = (bf16*)R;
    }

    // setup: weight cvt + mods + bias3 (one kernel)
    setup_kernel<<<20795, 256, 0, stream>>>(Wq, Wk, Wv, Wo, Winv, Wpt, wqkv, wib,
                                            sst, temb, modsb, bq_, bk_, bv_, bqkv);
    rmsmod_kernel<float><<<NTOK, 256, 0, stream>>>(h_in, modsb, 0, 1, bx);

    // fused QKV: (8192 x 1152) @ (3456 x 1152)^T -> qkvb
    gemm_kernel<0, bf16><<<dim3(NTOK / 128, QKVN / 128), 256, 0, stream>>>(
        bx, wqkv, bqkv, nullptr, 0, 0, nullptr, qkvb, QKVN, DIMC, DIMC, 0, 0, 1 << 30);

    // linear attention: MFMA KV (per-chunk partials) + reduce + MFMA out
    attn_kv_kernel<<<dim3(KV_CHUNKS, 16, 2), 256, 0, stream>>>(qkvb, kvpart);
    kvred_kernel<<<(32 * KVH + 255) / 256, 256, 0, stream>>>(kvpart, kvb);
    attn_out_kernel<<<dim3(32, 16, 2), 256, 0, stream>>>(qkvb, kvb, bx);
    // Wo + gate_msa*attn + resid(h_in) -> trunk
    gemm_kernel<2, bf16><<<dim3(NTOK / 128, DIMC / 128), 256, 0, stream>>>(
        bx, wob, bo_, modsb, 2, 0, h_in, trunk, DIMC, DIMC, DIMC, 0, 0, 1 << 30);
    // y = rms(trunk)*(1+scale_mlp)+shift_mlp -> bx
    rmsmod_kernel<bf16><<<NTOK, 256, 0, stream>>>(trunk, modsb, 3, 4, bx);

    if (tier0) {
        // ---- round-10 path: per-batch W_inv/dwglu into merged bglu, one MODE-6 W_pt ----
        bf16* bglu = (bf16*)R;                              // merged 8192 x 4608
        bf16* bbig = (bf16*)(R + BGLU2);                    // per-batch 4096 x 9216
        for (int b = 0; b < 2; ++b) {
            const bf16* Ainv = bx + (size_t)b * NSEQ * DIMC;
            // W_inv + SiLU: reads bx (intact for b=1: dwglu(b=0) wrote only bglu[0,37.7))
            gemm_kernel<3, bf16><<<dim3(NSEQ / 128, HID2 / 128), 256, 0, stream>>>(
                Ainv, wib, binv, nullptr, 0, 0, nullptr, bbig, HID2, DIMC, DIMC, 0, 0, 1 << 30);
            // dwglu -> merged bglu at batch offset (overwrites qkvb / then bx, both dead)
            dwglu_kernel<<<dim3(NSEQ), 576, 0, stream>>>(
                bbig, Wdw, bdw, 0, 0, bglu + (size_t)b * NSEQ * HIDC);
        }
        // W_pt full-K + fused trunk+gate epilogue -> out
        gemm_kernel<6, float><<<dim3(NTOK / 128, DIMC / 128), 256, 0, stream>>>(
            bglu, wpb, nullptr, modsb, 5, 0, (const float*)trunk, out, DIMC, HIDC, HIDC,
            0, 0, 1 << 30);
    } else if (tier1) {
        // ---- per-batch FFN with split-K + reduce (round-8 path) ----
        bf16*  bglu = (bf16*)R;
        bf16*  bbig = (bf16*)(R + BGLU_B);
        float* partials = (float*)(R + BGLU_B);             // aliases bbig (dead after dwglu)
        for (int b = 0; b < 2; ++b) {
            const bf16* Ainv = bx + (size_t)b * NSEQ * DIMC;
            gemm_kernel<3, bf16><<<dim3(NSEQ / 128, HID2 / 128), 256, 0, stream>>>(
                Ainv, wib, binv, nullptr, 0, 0, nullptr, bbig, HID2, DIMC, DIMC, 0, 0, 1 << 30);
            dwglu_kernel<<<dim3(NSEQ), 576, 0, stream>>>(bbig, Wdw, bdw, 0, 0, bglu);
            gemm_kernel<5, float><<<dim3(32, DIMC / 128, 2), 256, 0, stream>>>(
                bglu, wpb, nullptr, nullptr, 0, 0, nullptr, partials, DIMC, HIDC, HIDC / 2,
                PZB, 0, 1 << 30);
            reduce_kernel<2><<<(int)(PZB / 1024), 256, 0, stream>>>(partials, trunk, modsb, b, 0,
                                                                    PZB, out);
        }
    } else {
        // ---- fallback: 2048-row chunks with 128-row halo ----
        bf16*  bglu_c   = (bf16*)R;                         // 2048 x 4608 bf16
        bf16*  bbig_c   = (bf16*)(R + (size_t)18874368);    // 2304 x 9216 bf16
        float* partials = (float*)(R + (size_t)18874368);   // 4 x 2048 x 1152 f32 (aliases bbig)
        for (int b = 0; b < 2; ++b) {
            for (int c = 0; c < 2; ++c) {
                int r0 = c * 2048;
                int lo = (c == 0) ? 1 : 0;
                int hi = (c == 0) ? 18 : 17;
                const bf16* Ainv = bx + ((size_t)(b * NSEQ + r0)) * DIMC - (size_t)128 * DIMC;
                gemm_kernel<3, bf16><<<dim3(18, HID2 / 128), 256, 0, stream>>>(
                    Ainv, wib, binv, nullptr, 0, 0, nullptr, bbig_c, HID2, DIMC, DIMC, 0, lo, hi);
                dwglu_kernel<<<dim3(2048), 576, 0, stream>>>(bbig_c, Wdw, bdw, r0, 128, bglu_c);
                gemm_kernel<5, float><<<dim3(16, DIMC / 128, 4), 256, 0, stream>>>(
                    bglu_c, wpb, nullptr, nullptr, 0, 0, nullptr, partials, DIMC, HIDC, HIDC / 4,
                    PZ, 0, 1 << 30);
                reduce_kernel<4><<<(int)(PZ / 1024), 256, 0, stream>>>(partials, trunk, modsb, b,
                                                                       r0, PZ, out);
            }
        }
    }
}